// Round 10
// baseline (866.508 us; speedup 1.0000x reference)
//
#include <hip/hip_runtime.h>
#include <hip/hip_bf16.h>
#include <math.h>

#define Nn 768
#define Ff 64
#define Vv 16
#define NBb 8
#define HRr 64
#define Pp 176
#define TBL 1024
#define ROWC 176              // table cols per row: r1[64] r3[64] r2[16] r4[16] r5[16]
#define RMAXF 10.0f
#define AVGF 767.0f
#define SCALE 102.4f          // TBL / RMAX

// workspace float offsets (audited non-overlapping):
//   COM 0..2 | ES0 16..79 | XP 128..3199 | HSB 4096..28671 | HVB 28672..53247
//   OS 53248..77823 | OV 77824..114687 | CNT0 122880..123647 | CNT1 123648..124415
//   SLAB0 131072..917503 | SLAB1 917504..2097151 | TBL 2097152..
#define WS_COM   0
#define WS_ES0   16
#define WS_XP    128          // 768 x float4
#define WS_HSB   4096         // uint2[768][16]  : h_s^1 packed bf16 (4/uint2)
#define WS_HVB   28672        // uint2[768][16]  : h_v^1 packed bf16 (x,y,z,0)
#define WS_OS    53248        // [768][32] layer-0 scalar readout
#define WS_OV    77824        // [768][48] layer-0 vector readout ([k][c])
#define WS_CNT0  122880       // int[768] ticket counters, layer 0  (was 110592: overlapped OV!)
#define WS_CNT1  123648       // int[768] ticket counters, layer 1  (was 111360: overlapped OV!)
#define WS_SLAB0 131072       // float[4][768][256]
#define WS_SLAB1 917504       // float[4][768][384] (368 used)
#define WS_TBL   2097152      // unsigned[2][1025][176]: packed bf16 pairs (row,row+1)

__device__ __forceinline__ unsigned short f2bf(float f) {
  unsigned b = __float_as_uint(f);
  return (unsigned short)((b + 0x7fffu + ((b >> 16) & 1u)) >> 16);
}
__device__ __forceinline__ float lp(unsigned u, float f) {   // lerp packed pair
  float a = __uint_as_float(u << 16);
  float b = __uint_as_float(u & 0xffff0000u);
  return fmaf(f, b - a, a);
}
__device__ __forceinline__ float bl(unsigned u) { return __uint_as_float(u << 16); }
__device__ __forceinline__ float bh(unsigned u) { return __uint_as_float(u & 0xffff0000u); }

// ---------------------------------------------------------------- setup -----
// blocks 0..255: radial tables (t = b>>7, pair-rows (b&127)*8 ..+7)
// block 256: com + zero cnt0; 257: padded positions + zero cnt1; 258: es0
__global__ __launch_bounds__(256) void k_setup(const float* __restrict__ x,
                                               const float* __restrict__ embed,
                                               const float* __restrict__ wns,
                                               const float* __restrict__ w1,
                                               const float* __restrict__ b1,
                                               const float* __restrict__ w2,
                                               float* __restrict__ ws) {
  const int b = blockIdx.x, tid = threadIdx.x;
  if (b >= 256) {
    if (b == 256) {
      __shared__ float red[256][3];
      float a0 = 0, a1 = 0, a2 = 0;
      for (int n = tid; n < Nn; n += 256) {
        a0 += x[n * 3 + 0]; a1 += x[n * 3 + 1]; a2 += x[n * 3 + 2];
      }
      red[tid][0] = a0; red[tid][1] = a1; red[tid][2] = a2;
      __syncthreads();
      if (tid < 3) {
        float a = 0;
        for (int k = 0; k < 256; ++k) a += red[k][tid];
        ws[WS_COM + tid] = a * (1.0f / Nn);
      }
      int* c0 = (int*)(ws + WS_CNT0);
      for (int n = tid; n < Nn; n += 256) c0[n] = 0;
    } else if (b == 257) {
      for (int n = tid; n < Nn; n += 256) {
        ws[WS_XP + n * 4 + 0] = x[n * 3 + 0];
        ws[WS_XP + n * 4 + 1] = x[n * 3 + 1];
        ws[WS_XP + n * 4 + 2] = x[n * 3 + 2];
        ws[WS_XP + n * 4 + 3] = 0.0f;
      }
      int* c1 = (int*)(ws + WS_CNT1);
      for (int n = tid; n < Nn; n += 256) c1[n] = 0;
    } else {
      if (tid < 64) {
        float a = 0;
        for (int k = 0; k < 64; ++k) a = fmaf(embed[k], wns[k * 64 + tid], a);
        ws[WS_ES0 + tid] = a;
      }
    }
    return;
  }
  // ---- table block
  __shared__ float w2s[64][Pp];
  __shared__ float w1s[NBb][64];
  __shared__ float b1s[64];
  __shared__ float hid[9][65];
  const int t = b >> 7;
  const int r0 = (b & 127) * 8;
  const float* W2 = w2 + t * HRr * Pp;
  for (int k = tid; k < 64 * Pp; k += 256) w2s[k / Pp][k % Pp] = W2[k];
  for (int k = tid; k < NBb * 64; k += 256) w1s[k >> 6][k & 63] = w1[t * NBb * 64 + k];
  if (tid < 64) b1s[tid] = b1[t * 64 + tid];
  __syncthreads();
  {
    int rl4 = tid >> 6, h = tid & 63;
    const float c0 = 0.447213595f;               // sqrt(2/RMAX)
    const float pif = 3.14159265358979f;
    for (int pass = 0; pass < 3; ++pass) {
      int row_l = pass * 4 + rl4;
      if (row_l < 9) {
        int row = r0 + row_l;
        float r = row * (RMAXF / TBL);
        float acc = b1s[h];
        if (row == 0) {
          for (int n = 0; n < NBb; ++n) acc = fmaf(c0 * (n + 1) * (pif / RMAXF), w1s[n][h], acc);
        } else {
          float inv = 1.0f / r;
          for (int n = 0; n < NBb; ++n)
            acc = fmaf(c0 * sinf((n + 1) * pif * r / RMAXF) * inv, w1s[n][h], acc);
        }
        hid[row_l][h] = acc / (1.0f + expf(-acc));
      }
    }
  }
  __syncthreads();
  unsigned* T = (unsigned*)(ws + WS_TBL) + t * 1025 * ROWC;
  const int rl = tid & 7, colg = tid >> 3;       // 32 colgs x 6 cols (>=176 skipped)
  const int rowa = r0 + rl;
  float ra = rowa * (RMAXF / TBL), rb = (rowa + 1) * (RMAXF / TBL);
  float ua = 2.0f * (1.0f - ra / RMAXF), ub = 2.0f * (1.0f - rb / RMAXF);
  float env_a = (ua > 0.0f) ? 1.2f * expf(-1.0f / ua) : 0.0f;
  float env_b = (ub > 0.0f) ? 1.2f * expf(-1.0f / ub) : 0.0f;
  float accA[6], accB[6];
  int pcol[6]; bool vc[6];
#pragma unroll
  for (int c = 0; c < 6; ++c) {
    int col = colg * 6 + c;
    bool valid = (col < 176);
    int p = 0;
    if (valid) {
      if (col < 64) p = col;                       // r1 <- R[:, 0:64]
      else if (col < 128) p = 80 + (col - 64);     // r3 <- R[:, 80:144]
      else if (col < 144) p = 64 + (col - 128);    // r2 <- R[:, 64:80]
      else p = col;                                // r4 <- R[:,144:160], r5 <- R[:,160:176]
    }
    pcol[c] = p; vc[c] = valid; accA[c] = 0.0f; accB[c] = 0.0f;
  }
  for (int h = 0; h < 64; ++h) {
    float ha = hid[rl][h], hb = hid[rl + 1][h];
#pragma unroll
    for (int c = 0; c < 6; ++c) {
      float w = w2s[h][pcol[c]];
      accA[c] = fmaf(ha, w, accA[c]);
      accB[c] = fmaf(hb, w, accB[c]);
    }
  }
#pragma unroll
  for (int c = 0; c < 6; ++c) {
    if (vc[c]) {
      int col = colg * 6 + c;
      float va = accA[c] * env_a;
      float vb = accB[c] * env_b;
      T[rowa * ROWC + col] = ((unsigned)f2bf(vb) << 16) | (unsigned)f2bf(va);
    }
  }
  if ((b & 127) == 127) {                        // zero row 1024 (self / r>=RMAX)
    for (int k = tid; k < ROWC; k += 256) T[1024 * ROWC + k] = 0u;
  }
}

// ------------------------------------------------------------- edge t=0 -----
// 3072 blocks (4 parts/receiver), 256 thr. Pipelined loop -> slab write ->
// device-scope ticket; 4th block of each receiver runs the post-epilogue.
__global__ __launch_bounds__(256) void k_edge0(const float* __restrict__ wns,
                                               const float* __restrict__ wnv,
                                               const float* __restrict__ wmixs,
                                               const float* __restrict__ wmixv,
                                               const float* __restrict__ wgate,
                                               const float* __restrict__ wros,
                                               const float* __restrict__ wrov,
                                               float* __restrict__ ws) {
  const int blk = blockIdx.x, i = blk >> 2, part = blk & 3;
  const int tid = threadIdx.x;
  const int w = tid >> 6, lane = tid & 63, sq = (lane >> 4) & 3, idx = lane & 15;
  __shared__ float4 GEO[192];
  __shared__ float wb[4][16][17];    // odd stride: conflict-free
  __shared__ int ticket;
  const float4* XP4 = (const float4*)(ws + WS_XP);
  const unsigned* T0 = (const unsigned*)(ws + WS_TBL);
  const float4 xi = XP4[i];
  if (tid < 192) {
    int j = part * 192 + tid;
    float4 xj = XP4[j];
    float dx = xi.x - xj.x, dy = xi.y - xj.y, dz = xi.z - xj.z;
    float r2 = dx * dx + dy * dy + dz * dz;
    float u, hx, hy, hz;
    if (j == i || r2 <= 0.0f) { u = 1024.0f; hx = hy = hz = 0.0f; }
    else {
      float rinv = rsqrtf(r2);
      hx = dx * rinv; hy = dy * rinv; hz = dz * rinv;
      u = fminf(r2 * rinv * SCALE, 1024.0f);
    }
    GEO[tid] = make_float4(hx, hy, hz, u);
  }
  __syncthreads();
  float s1[4] = {0, 0, 0, 0};
  float v1[4][3] = {};
  const int base = w * 48 + sq;
  // ---- pipeline prologue: load iter 0
  float4 g = GEO[base];
  int i0 = (int)g.w;
  float fr = g.w - (float)i0;
  const uint4* rp = (const uint4*)(T0 + i0 * ROWC);
  uint4 t1 = rp[idx];
  uint4 t3 = rp[16 + idx];
  for (int q = 0; q < 12; ++q) {
    float4 gc = g; float frc = fr;
    uint4 t1c = t1, t3c = t3;
    if (q < 11) {
      g = GEO[base + (q + 1) * 4];
      i0 = (int)g.w;
      fr = g.w - (float)i0;
      const uint4* rpn = (const uint4*)(T0 + i0 * ROWC);
      t1 = rpn[idx];
      t3 = rpn[16 + idx];
    }
    s1[0] += lp(t1c.x, frc); s1[1] += lp(t1c.y, frc);
    s1[2] += lp(t1c.z, frc); s1[3] += lp(t1c.w, frc);
    float ax = lp(t3c.x, frc), ay = lp(t3c.y, frc), az = lp(t3c.z, frc), aw = lp(t3c.w, frc);
    v1[0][0] += ax * gc.x; v1[0][1] += ax * gc.y; v1[0][2] += ax * gc.z;
    v1[1][0] += ay * gc.x; v1[1][1] += ay * gc.y; v1[1][2] += ay * gc.z;
    v1[2][0] += az * gc.x; v1[2][1] += az * gc.y; v1[2][2] += az * gc.z;
    v1[3][0] += aw * gc.x; v1[3][1] += aw * gc.y; v1[3][2] += aw * gc.z;
  }
  float vals[16] = {s1[0], s1[1], s1[2], s1[3],
                    v1[0][0], v1[0][1], v1[0][2], v1[1][0], v1[1][1], v1[1][2],
                    v1[2][0], v1[2][1], v1[2][2], v1[3][0], v1[3][1], v1[3][2]};
#pragma unroll
  for (int k = 0; k < 16; ++k) {
    float v = vals[k];
    v += __shfl_xor(v, 16);
    v += __shfl_xor(v, 32);
    if (lane < 16) wb[w][lane][k] = v;
  }
  __syncthreads();
  {
    int l, s;
    if (tid < 64) { l = tid >> 2; s = tid & 3; }
    else { int p = tid - 64, f = p / 3, c = p - 3 * f; l = f >> 2; s = 4 + 3 * (f & 3) + c; }
    float a = wb[0][l][s] + wb[1][l][s] + wb[2][l][s] + wb[3][l][s];
    ws[WS_SLAB0 + (part * Nn + i) * 256 + tid] = a;
  }
  // ---- ticket: last of 4 blocks for receiver i runs the epilogue
  __threadfence();
  if (tid == 0) ticket = atomicAdd((int*)(ws + WS_CNT0) + i, 1);
  __syncthreads();
  if (ticket != 3) return;
  __threadfence();   // acquire: make other parts' slab writes visible
  __shared__ float agg[256];
  __shared__ float ms[64], mvv[16][3], gate[16], hsn[64], hvns[16][4];
  __shared__ float hs1s[64], hv1s[16][4];
  const float* S = ws + WS_SLAB0 + i * 256;
  {
    float a = S[tid] + S[Nn * 256 + tid] + S[2 * Nn * 256 + tid] + S[3 * Nn * 256 + tid];
    float es0f = (tid < 64) ? ws[WS_ES0 + tid] : ws[WS_ES0 + (tid - 64) / 3];
    agg[tid] = a * (1.0f / AVGF) * es0f;
  }
  __syncthreads();
  if (tid < 64) {                    // dot-slots of wmixs rows 64..79 are 0 at t=0
    float a = 0;
    for (int p = 0; p < 64; ++p) a = fmaf(agg[p], wmixs[p * 64 + tid], a);
    ms[tid] = a;
  } else if (tid < 112) {            // v2/v3 rows of wmixv are 0 at t=0
    int c = (tid - 64) >> 4, v = (tid - 64) & 15;
    float a = 0;
    for (int p = 0; p < 64; ++p) a = fmaf(agg[64 + p * 3 + c], wmixv[p * 16 + v], a);
    mvv[v][c] = a;
  }
  __syncthreads();
  if (tid < 64) {
    float m = ms[tid];
    hsn[tid] = m / (1.0f + expf(-m));
  } else if (tid < 80) {
    int v = tid - 64;
    float a = 0;
    for (int f = 0; f < 64; ++f) a = fmaf(ms[f], wgate[f * 16 + v], a);
    gate[v] = 1.0f / (1.0f + expf(-a));
  }
  __syncthreads();
  if (tid < 64) {
    int v = tid >> 2, c = tid & 3;
    hvns[v][c] = (c < 3) ? gate[v] * mvv[v][c] : 0.0f;
  }
  __syncthreads();
  if (tid < 32) {
    float a = 0;
    for (int f = 0; f < 64; ++f) a = fmaf(hsn[f], wros[f * 32 + tid], a);
    ws[WS_OS + i * 32 + tid] = a;
  } else if (tid < 80) {
    int p = tid - 32, k = p / 3, c = p - 3 * k;
    float a = 0;
    for (int v = 0; v < 16; ++v) a = fmaf(hvns[v][c], wrov[v * 16 + k], a);
    ws[WS_OV + i * 48 + p] = a;
  } else if (tid < 144) {
    int f2 = tid - 80;
    const float* Wn = wns + 64 * 64;               // wns[1]
    float a = 0;
    for (int f = 0; f < 64; ++f) a = fmaf(hsn[f], Wn[f * 64 + f2], a);
    hs1s[f2] = a;
  } else if (tid < 208) {
    int s = tid - 144, wv = s >> 2, c = s & 3;
    float a = 0;
    if (c < 3) {
      const float* Wn = wnv + 16 * 16;             // wnv[1]
      for (int v = 0; v < 16; ++v) a = fmaf(hvns[v][c], Wn[v * 16 + wv], a);
    }
    hv1s[wv][c] = a;
  }
  __syncthreads();
  if (tid < 16) {                                  // pack h_s^1 -> bf16x4
    uint2* HSB = (uint2*)(ws + WS_HSB);
    unsigned u0 = (unsigned)f2bf(hs1s[4 * tid + 0]) | ((unsigned)f2bf(hs1s[4 * tid + 1]) << 16);
    unsigned u1 = (unsigned)f2bf(hs1s[4 * tid + 2]) | ((unsigned)f2bf(hs1s[4 * tid + 3]) << 16);
    HSB[i * 16 + tid] = make_uint2(u0, u1);
  } else if (tid < 32) {                           // pack h_v^1 -> bf16 (x,y,z,0)
    int v = tid - 16;
    uint2* HVB = (uint2*)(ws + WS_HVB);
    unsigned u0 = (unsigned)f2bf(hv1s[v][0]) | ((unsigned)f2bf(hv1s[v][1]) << 16);
    unsigned u1 = (unsigned)f2bf(hv1s[v][2]);
    HVB[i * 16 + v] = make_uint2(u0, u1);
  }
}

// ------------------------------------------------------------- edge t=1 -----
// Same structure: pipelined loop -> slab -> ticket -> final epilogue to out.
__global__ __launch_bounds__(256) void k_edge1(const float* __restrict__ wmixs,
                                               const float* __restrict__ wmixv,
                                               const float* __restrict__ wgate,
                                               const float* __restrict__ wros,
                                               const float* __restrict__ wrov,
                                               float* __restrict__ ws,
                                               float* __restrict__ out) {
  const int blk = blockIdx.x, i = blk >> 2, part = blk & 3;
  const int tid = threadIdx.x;
  const int w = tid >> 6, lane = tid & 63, sq = (lane >> 4) & 3, idx = lane & 15;
  __shared__ float4 GEO[192];
  __shared__ float wb[4][16][25];    // odd stride: conflict-free
  __shared__ int ticket;
  const float4* XP4 = (const float4*)(ws + WS_XP);
  const unsigned* T1 = (const unsigned*)(ws + WS_TBL) + 1025 * ROWC;  // t=1
  const uint2* HSB = (const uint2*)(ws + WS_HSB);
  const uint2* HVB = (const uint2*)(ws + WS_HVB);
  const float4 xi = XP4[i];
  if (tid < 192) {
    int j = part * 192 + tid;
    float4 xj = XP4[j];
    float dx = xi.x - xj.x, dy = xi.y - xj.y, dz = xi.z - xj.z;
    float r2 = dx * dx + dy * dy + dz * dz;
    float u, hx, hy, hz;
    if (j == i || r2 <= 0.0f) { u = 1024.0f; hx = hy = hz = 0.0f; }
    else {
      float rinv = rsqrtf(r2);
      hx = dx * rinv; hy = dy * rinv; hz = dz * rinv;
      u = fminf(r2 * rinv * SCALE, 1024.0f);
    }
    GEO[tid] = make_float4(hx, hy, hz, u);
  }
  __syncthreads();
  float s1[4] = {0, 0, 0, 0};
  float v1[4][3] = {};
  float s2 = 0, v2x = 0, v2y = 0, v2z = 0, v3x = 0, v3y = 0, v3z = 0;
  const int jbase = part * 192;
  const int base = w * 48 + sq;
  // ---- pipeline prologue: load iter 0
  float4 g = GEO[base];
  int i0 = (int)g.w;
  float fr = g.w - (float)i0;
  const unsigned* row = T1 + i0 * ROWC;
  uint4 t1 = ((const uint4*)row)[idx];
  uint4 t3 = ((const uint4*)row)[16 + idx];
  unsigned u2 = row[128 + idx];
  unsigned u4 = row[144 + idx];
  unsigned u5 = row[160 + idx];
  uint2 esb = HSB[(jbase + base) * 16 + idx];
  uint2 evb = HVB[(jbase + base) * 16 + idx];
  for (int q = 0; q < 12; ++q) {
    float4 gc = g; float frc = fr;
    uint4 t1c = t1, t3c = t3;
    unsigned u2c = u2, u4c = u4, u5c = u5;
    uint2 esc = esb, evc = evb;
    if (q < 11) {
      int jl = base + (q + 1) * 4;
      g = GEO[jl];
      i0 = (int)g.w;
      fr = g.w - (float)i0;
      const unsigned* rn = T1 + i0 * ROWC;
      t1 = ((const uint4*)rn)[idx];
      t3 = ((const uint4*)rn)[16 + idx];
      u2 = rn[128 + idx];
      u4 = rn[144 + idx];
      u5 = rn[160 + idx];
      esb = HSB[(jbase + jl) * 16 + idx];
      evb = HVB[(jbase + jl) * 16 + idx];
    }
    float esx = bl(esc.x), esy = bh(esc.x), esz = bl(esc.y), esw = bh(esc.y);
    float evx = bl(evc.x), evy = bh(evc.x), evz = bl(evc.y);
    s1[0] += esx * lp(t1c.x, frc); s1[1] += esy * lp(t1c.y, frc);
    s1[2] += esz * lp(t1c.z, frc); s1[3] += esw * lp(t1c.w, frc);
    float ax = esx * lp(t3c.x, frc), ay = esy * lp(t3c.y, frc);
    float az = esz * lp(t3c.z, frc), aw = esw * lp(t3c.w, frc);
    v1[0][0] += ax * gc.x; v1[0][1] += ax * gc.y; v1[0][2] += ax * gc.z;
    v1[1][0] += ay * gc.x; v1[1][1] += ay * gc.y; v1[1][2] += ay * gc.z;
    v1[2][0] += az * gc.x; v1[2][1] += az * gc.y; v1[2][2] += az * gc.z;
    v1[3][0] += aw * gc.x; v1[3][1] += aw * gc.y; v1[3][2] += aw * gc.z;
    float rr2 = lp(u2c, frc), rr4 = lp(u4c, frc), rr5 = lp(u5c, frc);
    float dt = evx * gc.x + evy * gc.y + evz * gc.z;
    s2 += dt * rr2;
    v2x += evx * rr4; v2y += evy * rr4; v2z += evz * rr4;
    v3x += (evy * gc.z - evz * gc.y) * rr5;
    v3y += (evz * gc.x - evx * gc.z) * rr5;
    v3z += (evx * gc.y - evy * gc.x) * rr5;
  }
  float vals[23] = {s1[0], s1[1], s1[2], s1[3],
                    v1[0][0], v1[0][1], v1[0][2], v1[1][0], v1[1][1], v1[1][2],
                    v1[2][0], v1[2][1], v1[2][2], v1[3][0], v1[3][1], v1[3][2],
                    s2, v2x, v2y, v2z, v3x, v3y, v3z};
#pragma unroll
  for (int k = 0; k < 23; ++k) {
    float v = vals[k];
    v += __shfl_xor(v, 16);
    v += __shfl_xor(v, 32);
    if (lane < 16) wb[w][lane][k] = v;
  }
  __syncthreads();
  for (int s = tid; s < 368; s += 256) {
    int l, sl;
    if (s < 64) { l = s >> 2; sl = s & 3; }
    else if (s < 80) { l = s - 64; sl = 16; }
    else if (s < 272) { int p = s - 80, f = p / 3, c = p - 3 * f; l = f >> 2; sl = 4 + 3 * (f & 3) + c; }
    else if (s < 320) { int p = s - 272, v = p / 3, c = p - 3 * v; l = v; sl = 17 + c; }
    else { int p = s - 320, v = p / 3, c = p - 3 * v; l = v; sl = 20 + c; }
    ws[WS_SLAB1 + (part * Nn + i) * 384 + s] =
        wb[0][l][sl] + wb[1][l][sl] + wb[2][l][sl] + wb[3][l][sl];
  }
  // ---- ticket: last of 4 blocks runs final epilogue
  __threadfence();
  if (tid == 0) ticket = atomicAdd((int*)(ws + WS_CNT1) + i, 1);
  __syncthreads();
  if (ticket != 3) return;
  __threadfence();
  __shared__ float agg[368];
  __shared__ float ms[64], mvv[16][3], gate[16], hsn[64], hvns[16][4];
  const float* S = ws + WS_SLAB1 + i * 384;
  for (int s = tid; s < 368; s += 256)
    agg[s] = (S[s] + S[Nn * 384 + s] + S[2 * Nn * 384 + s] + S[3 * Nn * 384 + s]) * (1.0f / AVGF);
  __syncthreads();
  if (tid < 64) {
    const float* Wm = wmixs + 80 * 64;             // wmixs[1]
    float a = 0;
    for (int p = 0; p < 80; ++p) a = fmaf(agg[p], Wm[p * 64 + tid], a);
    ms[tid] = a;
  } else if (tid < 112) {
    int c = (tid - 64) >> 4, v = (tid - 64) & 15;
    const float* Wv = wmixv + 96 * 16;             // wmixv[1]
    float a = 0;
    for (int p = 0; p < 96; ++p) {
      int ai = (p < 64) ? (80 + p * 3 + c) : (p < 80 ? (272 + (p - 64) * 3 + c)
                                                     : (320 + (p - 80) * 3 + c));
      a = fmaf(agg[ai], Wv[p * 16 + v], a);
    }
    mvv[v][c] = a;
  }
  __syncthreads();
  if (tid < 64) {
    float m = ms[tid];
    hsn[tid] = m / (1.0f + expf(-m));
  } else if (tid < 80) {
    int v = tid - 64;
    const float* Wg = wgate + 64 * 16;             // wgate[1]
    float a = 0;
    for (int f = 0; f < 64; ++f) a = fmaf(ms[f], Wg[f * 16 + v], a);
    gate[v] = 1.0f / (1.0f + expf(-a));
  }
  __syncthreads();
  if (tid < 64) {
    int v = tid >> 2, c = tid & 3;
    hvns[v][c] = (c < 3) ? gate[v] * mvv[v][c] : 0.0f;
  }
  __syncthreads();
  if (tid < 32) {
    const float* Wr = wros + 64 * 32;              // wros[1]
    float a = ws[WS_OS + i * 32 + tid];
    for (int f = 0; f < 64; ++f) a = fmaf(hsn[f], Wr[f * 32 + tid], a);
    out[i * 32 + tid] = a;
  } else if (tid < 80) {
    int p = tid - 32, k = p / 3, c = p - 3 * k;
    const float* Wr = wrov + 16 * 16;              // wrov[1]
    float a = ws[WS_OV + i * 48 + p] + ws[WS_COM + c];
    for (int v = 0; v < 16; ++v) a = fmaf(hvns[v][c], Wr[v * 16 + k], a);
    out[Nn * 32 + i * 48 + p] = a;
  }
}

// ------------------------------------------------------------- launch -------
extern "C" void kernel_launch(void* const* d_in, const int* in_sizes, int n_in,
                              void* d_out, int out_size, void* d_ws, size_t ws_size,
                              hipStream_t stream) {
  const float* x     = (const float*)d_in[0];
  const float* embed = (const float*)d_in[1];
  const float* wns   = (const float*)d_in[2];
  const float* wnv   = (const float*)d_in[3];
  const float* w1    = (const float*)d_in[4];
  const float* b1    = (const float*)d_in[5];
  const float* w2    = (const float*)d_in[6];
  const float* wmixs = (const float*)d_in[7];
  const float* wmixv = (const float*)d_in[8];
  const float* wgate = (const float*)d_in[9];
  const float* wros  = (const float*)d_in[10];
  const float* wrov  = (const float*)d_in[11];
  float* ws = (float*)d_ws;
  float* out = (float*)d_out;

  hipLaunchKernelGGL(k_setup, dim3(259),    dim3(256), 0, stream, x, embed, wns, w1, b1, w2, ws);
  hipLaunchKernelGGL(k_edge0, dim3(Nn * 4), dim3(256), 0, stream,
                     wns, wnv, wmixs, wmixv, wgate, wros, wrov, ws);
  hipLaunchKernelGGL(k_edge1, dim3(Nn * 4), dim3(256), 0, stream,
                     wmixs, wmixv, wgate, wros, wrov, ws, out);
}

// Round 11
// 154.240 us; speedup vs baseline: 5.6179x; 5.6179x over previous
//
#include <hip/hip_runtime.h>
#include <hip/hip_bf16.h>
#include <math.h>

#define Nn 768
#define Ff 64
#define Vv 16
#define NBb 8
#define HRr 64
#define Pp 176
#define TBL 1024
#define ROWC 176              // table cols per row: r1[64] r3[64] r2[16] r4[16] r5[16]
#define RMAXF 10.0f
#define AVGF 767.0f
#define SCALE 102.4f          // TBL / RMAX

// workspace float offsets
#define WS_COM   0
#define WS_ES0   16
#define WS_XP    128          // 768 x float4
#define WS_HSB   4096         // uint2[768][16]  : h_s^1 packed bf16 (4/uint2)
#define WS_HVB   28672        // uint2[768][16]  : h_v^1 packed bf16 (x,y,z,0)
#define WS_OS    53248        // [768][32] layer-0 scalar readout
#define WS_OV    77824        // [768][48] layer-0 vector readout ([k][c])
#define WS_SLAB0 131072       // float[4][768][256]
#define WS_SLAB1 917504       // float[4][768][384] (368 used)
#define WS_TBL   2097152      // unsigned[2][1025][176]: packed bf16 pairs (row,row+1)

__device__ __forceinline__ unsigned short f2bf(float f) {
  unsigned b = __float_as_uint(f);
  return (unsigned short)((b + 0x7fffu + ((b >> 16) & 1u)) >> 16);
}
__device__ __forceinline__ float lp(unsigned u, float f) {   // lerp packed pair
  float a = __uint_as_float(u << 16);
  float b = __uint_as_float(u & 0xffff0000u);
  return fmaf(f, b - a, a);
}
__device__ __forceinline__ float bl(unsigned u) { return __uint_as_float(u << 16); }
__device__ __forceinline__ float bh(unsigned u) { return __uint_as_float(u & 0xffff0000u); }

// ---------------------------------------------------------------- setup -----
// blocks 0..255: radial tables (t = b>>7, pair-rows (b&127)*8 ..+7)
// block 256: center of mass; 257: padded positions; 258: es0 = embed @ wns[0]
__global__ __launch_bounds__(256) void k_setup(const float* __restrict__ x,
                                               const float* __restrict__ embed,
                                               const float* __restrict__ wns,
                                               const float* __restrict__ w1,
                                               const float* __restrict__ b1,
                                               const float* __restrict__ w2,
                                               float* __restrict__ ws) {
  const int b = blockIdx.x, tid = threadIdx.x;
  if (b >= 256) {
    if (b == 256) {
      __shared__ float red[256][3];
      float a0 = 0, a1 = 0, a2 = 0;
      for (int n = tid; n < Nn; n += 256) {
        a0 += x[n * 3 + 0]; a1 += x[n * 3 + 1]; a2 += x[n * 3 + 2];
      }
      red[tid][0] = a0; red[tid][1] = a1; red[tid][2] = a2;
      __syncthreads();
      if (tid < 3) {
        float a = 0;
        for (int k = 0; k < 256; ++k) a += red[k][tid];
        ws[WS_COM + tid] = a * (1.0f / Nn);
      }
    } else if (b == 257) {
      for (int n = tid; n < Nn; n += 256) {
        ws[WS_XP + n * 4 + 0] = x[n * 3 + 0];
        ws[WS_XP + n * 4 + 1] = x[n * 3 + 1];
        ws[WS_XP + n * 4 + 2] = x[n * 3 + 2];
        ws[WS_XP + n * 4 + 3] = 0.0f;
      }
    } else {
      if (tid < 64) {
        float a = 0;
        for (int k = 0; k < 64; ++k) a = fmaf(embed[k], wns[k * 64 + tid], a);
        ws[WS_ES0 + tid] = a;
      }
    }
    return;
  }
  // ---- table block
  __shared__ float w2s[64][Pp];
  __shared__ float w1s[NBb][64];
  __shared__ float b1s[64];
  __shared__ float hid[9][65];
  const int t = b >> 7;
  const int r0 = (b & 127) * 8;
  const float* W2 = w2 + t * HRr * Pp;
  for (int k = tid; k < 64 * Pp; k += 256) w2s[k / Pp][k % Pp] = W2[k];
  for (int k = tid; k < NBb * 64; k += 256) w1s[k >> 6][k & 63] = w1[t * NBb * 64 + k];
  if (tid < 64) b1s[tid] = b1[t * 64 + tid];
  __syncthreads();
  {
    int rl4 = tid >> 6, h = tid & 63;
    const float c0 = 0.447213595f;               // sqrt(2/RMAX)
    const float pif = 3.14159265358979f;
    for (int pass = 0; pass < 3; ++pass) {
      int row_l = pass * 4 + rl4;
      if (row_l < 9) {
        int row = r0 + row_l;
        float r = row * (RMAXF / TBL);
        float acc = b1s[h];
        if (row == 0) {
          for (int n = 0; n < NBb; ++n) acc = fmaf(c0 * (n + 1) * (pif / RMAXF), w1s[n][h], acc);
        } else {
          float inv = 1.0f / r;
          for (int n = 0; n < NBb; ++n)
            acc = fmaf(c0 * sinf((n + 1) * pif * r / RMAXF) * inv, w1s[n][h], acc);
        }
        hid[row_l][h] = acc / (1.0f + expf(-acc));
      }
    }
  }
  __syncthreads();
  unsigned* T = (unsigned*)(ws + WS_TBL) + t * 1025 * ROWC;
  const int rl = tid & 7, colg = tid >> 3;       // 32 colgs x 6 cols (>=176 skipped)
  const int rowa = r0 + rl;
  float ra = rowa * (RMAXF / TBL), rb = (rowa + 1) * (RMAXF / TBL);
  float ua = 2.0f * (1.0f - ra / RMAXF), ub = 2.0f * (1.0f - rb / RMAXF);
  float env_a = (ua > 0.0f) ? 1.2f * expf(-1.0f / ua) : 0.0f;
  float env_b = (ub > 0.0f) ? 1.2f * expf(-1.0f / ub) : 0.0f;
  float accA[6], accB[6];
  int pcol[6]; bool vc[6];
#pragma unroll
  for (int c = 0; c < 6; ++c) {
    int col = colg * 6 + c;
    bool valid = (col < 176);
    int p = 0;
    if (valid) {
      if (col < 64) p = col;                       // r1 <- R[:, 0:64]
      else if (col < 128) p = 80 + (col - 64);     // r3 <- R[:, 80:144]
      else if (col < 144) p = 64 + (col - 128);    // r2 <- R[:, 64:80]
      else p = col;                                // r4 <- R[:,144:160], r5 <- R[:,160:176]
    }
    pcol[c] = p; vc[c] = valid; accA[c] = 0.0f; accB[c] = 0.0f;
  }
  for (int h = 0; h < 64; ++h) {
    float ha = hid[rl][h], hb = hid[rl + 1][h];
#pragma unroll
    for (int c = 0; c < 6; ++c) {
      float w = w2s[h][pcol[c]];
      accA[c] = fmaf(ha, w, accA[c]);
      accB[c] = fmaf(hb, w, accB[c]);
    }
  }
#pragma unroll
  for (int c = 0; c < 6; ++c) {
    if (vc[c]) {
      int col = colg * 6 + c;
      float va = accA[c] * env_a;
      float vb = accB[c] * env_b;
      T[rowa * ROWC + col] = ((unsigned)f2bf(vb) << 16) | (unsigned)f2bf(va);
    }
  }
  if ((b & 127) == 127) {                        // zero row 1024 (self / r>=RMAX)
    for (int k = tid; k < ROWC; k += 256) T[1024 * ROWC + k] = 0u;
  }
}

// ------------------------------------------------------------- edge t=0 -----
// 3072 blocks (4 parts/receiver). Only r1/r3 columns (es uniform, ev=0).
// Software-pipelined: iteration q+1's table loads issue before q's FMAs.
__global__ __launch_bounds__(256) void k_edge0(float* __restrict__ ws) {
  const int blk = blockIdx.x, i = blk >> 2, part = blk & 3;
  const int tid = threadIdx.x;
  const int w = tid >> 6, lane = tid & 63, sq = (lane >> 4) & 3, idx = lane & 15;
  __shared__ float4 GEO[192];
  __shared__ float wb[4][16][17];    // odd stride: conflict-free
  const float4* XP4 = (const float4*)(ws + WS_XP);
  const unsigned* T0 = (const unsigned*)(ws + WS_TBL);
  const float4 xi = XP4[i];
  if (tid < 192) {
    int j = part * 192 + tid;
    float4 xj = XP4[j];
    float dx = xi.x - xj.x, dy = xi.y - xj.y, dz = xi.z - xj.z;
    float r2 = dx * dx + dy * dy + dz * dz;
    float u, hx, hy, hz;
    if (j == i || r2 <= 0.0f) { u = 1024.0f; hx = hy = hz = 0.0f; }
    else {
      float rinv = rsqrtf(r2);
      hx = dx * rinv; hy = dy * rinv; hz = dz * rinv;
      u = fminf(r2 * rinv * SCALE, 1024.0f);
    }
    GEO[tid] = make_float4(hx, hy, hz, u);
  }
  __syncthreads();
  float s1[4] = {0, 0, 0, 0};
  float v1[4][3] = {};
  const int base = w * 48 + sq;
  // ---- pipeline prologue: load iter 0
  float4 g = GEO[base];
  int i0 = (int)g.w;
  float fr = g.w - (float)i0;
  const uint4* rp = (const uint4*)(T0 + i0 * ROWC);
  uint4 t1 = rp[idx];
  uint4 t3 = rp[16 + idx];
  for (int q = 0; q < 12; ++q) {
    // current stage registers
    float4 gc = g; float frc = fr;
    uint4 t1c = t1, t3c = t3;
    // prefetch next stage
    if (q < 11) {
      g = GEO[base + (q + 1) * 4];
      i0 = (int)g.w;
      fr = g.w - (float)i0;
      const uint4* rpn = (const uint4*)(T0 + i0 * ROWC);
      t1 = rpn[idx];
      t3 = rpn[16 + idx];
    }
    // compute with current
    s1[0] += lp(t1c.x, frc); s1[1] += lp(t1c.y, frc);
    s1[2] += lp(t1c.z, frc); s1[3] += lp(t1c.w, frc);
    float ax = lp(t3c.x, frc), ay = lp(t3c.y, frc), az = lp(t3c.z, frc), aw = lp(t3c.w, frc);
    v1[0][0] += ax * gc.x; v1[0][1] += ax * gc.y; v1[0][2] += ax * gc.z;
    v1[1][0] += ay * gc.x; v1[1][1] += ay * gc.y; v1[1][2] += ay * gc.z;
    v1[2][0] += az * gc.x; v1[2][1] += az * gc.y; v1[2][2] += az * gc.z;
    v1[3][0] += aw * gc.x; v1[3][1] += aw * gc.y; v1[3][2] += aw * gc.z;
  }
  float vals[16] = {s1[0], s1[1], s1[2], s1[3],
                    v1[0][0], v1[0][1], v1[0][2], v1[1][0], v1[1][1], v1[1][2],
                    v1[2][0], v1[2][1], v1[2][2], v1[3][0], v1[3][1], v1[3][2]};
#pragma unroll
  for (int k = 0; k < 16; ++k) {
    float v = vals[k];
    v += __shfl_xor(v, 16);
    v += __shfl_xor(v, 32);
    if (lane < 16) wb[w][lane][k] = v;
  }
  __syncthreads();
  {
    int l, s;
    if (tid < 64) { l = tid >> 2; s = tid & 3; }
    else { int p = tid - 64, f = p / 3, c = p - 3 * f; l = f >> 2; s = 4 + 3 * (f & 3) + c; }
    float a = wb[0][l][s] + wb[1][l][s] + wb[2][l][s] + wb[3][l][s];
    ws[WS_SLAB0 + (part * Nn + i) * 256 + tid] = a;
  }
}

// ------------------------------------------------------------- post t=0 -----
// Sum slabs, apply es0, node update, layer-0 readout, layer-1 node transforms
// packed to bf16 for k_edge1.
__global__ __launch_bounds__(256) void k_post0(const float* __restrict__ wns,
                                               const float* __restrict__ wnv,
                                               const float* __restrict__ wmixs,
                                               const float* __restrict__ wmixv,
                                               const float* __restrict__ wgate,
                                               const float* __restrict__ wros,
                                               const float* __restrict__ wrov,
                                               float* __restrict__ ws) {
  const int i = blockIdx.x, tid = threadIdx.x;
  __shared__ float agg[256];
  __shared__ float ms[64], mvv[16][3], gate[16], hsn[64], hvns[16][4];
  __shared__ float hs1s[64], hv1s[16][4];
  const float inv = 1.0f / AVGF;
  const float* S = ws + WS_SLAB0 + i * 256;
  {
    float a = S[tid] + S[Nn * 256 + tid] + S[2 * Nn * 256 + tid] + S[3 * Nn * 256 + tid];
    float es0f = (tid < 64) ? ws[WS_ES0 + tid] : ws[WS_ES0 + (tid - 64) / 3];
    agg[tid] = a * inv * es0f;
  }
  __syncthreads();
  if (tid < 64) {                    // dot-slots of wmixs rows 64..79 are 0 at t=0
    const float* Wm = wmixs;
    float a = 0;
    for (int p = 0; p < 64; ++p) a = fmaf(agg[p], Wm[p * 64 + tid], a);
    ms[tid] = a;
  } else if (tid < 112) {            // v2/v3 rows of wmixv are 0 at t=0
    int c = (tid - 64) >> 4, v = (tid - 64) & 15;
    const float* Wv = wmixv;
    float a = 0;
    for (int p = 0; p < 64; ++p) a = fmaf(agg[64 + p * 3 + c], Wv[p * 16 + v], a);
    mvv[v][c] = a;
  }
  __syncthreads();
  if (tid < 64) {
    float m = ms[tid];
    hsn[tid] = m / (1.0f + expf(-m));
  } else if (tid < 80) {
    int v = tid - 64;
    float a = 0;
    for (int f = 0; f < 64; ++f) a = fmaf(ms[f], wgate[f * 16 + v], a);
    gate[v] = 1.0f / (1.0f + expf(-a));
  }
  __syncthreads();
  if (tid < 64) {
    int v = tid >> 2, c = tid & 3;
    hvns[v][c] = (c < 3) ? gate[v] * mvv[v][c] : 0.0f;
  }
  __syncthreads();
  if (tid < 32) {
    float a = 0;
    for (int f = 0; f < 64; ++f) a = fmaf(hsn[f], wros[f * 32 + tid], a);
    ws[WS_OS + i * 32 + tid] = a;
  } else if (tid < 80) {
    int p = tid - 32, k = p / 3, c = p - 3 * k;
    float a = 0;
    for (int v = 0; v < 16; ++v) a = fmaf(hvns[v][c], wrov[v * 16 + k], a);
    ws[WS_OV + i * 48 + p] = a;
  } else if (tid < 144) {
    int f2 = tid - 80;
    const float* Wn = wns + 64 * 64;               // wns[1]
    float a = 0;
    for (int f = 0; f < 64; ++f) a = fmaf(hsn[f], Wn[f * 64 + f2], a);
    hs1s[f2] = a;
  } else if (tid < 208) {
    int s = tid - 144, wv = s >> 2, c = s & 3;
    float a = 0;
    if (c < 3) {
      const float* Wn = wnv + 16 * 16;             // wnv[1]
      for (int v = 0; v < 16; ++v) a = fmaf(hvns[v][c], Wn[v * 16 + wv], a);
    }
    hv1s[wv][c] = a;
  }
  __syncthreads();
  if (tid < 16) {                                  // pack h_s^1 -> bf16x4
    uint2* HSB = (uint2*)(ws + WS_HSB);
    unsigned u0 = (unsigned)f2bf(hs1s[4 * tid + 0]) | ((unsigned)f2bf(hs1s[4 * tid + 1]) << 16);
    unsigned u1 = (unsigned)f2bf(hs1s[4 * tid + 2]) | ((unsigned)f2bf(hs1s[4 * tid + 3]) << 16);
    HSB[i * 16 + tid] = make_uint2(u0, u1);
  } else if (tid < 32) {                           // pack h_v^1 -> bf16 (x,y,z,0)
    int v = tid - 16;
    uint2* HVB = (uint2*)(ws + WS_HVB);
    unsigned u0 = (unsigned)f2bf(hv1s[v][0]) | ((unsigned)f2bf(hv1s[v][1]) << 16);
    unsigned u1 = (unsigned)f2bf(hv1s[v][2]);
    HVB[i * 16 + v] = make_uint2(u0, u1);
  }
}

// ------------------------------------------------------------- edge t=1 -----
// Software-pipelined 1-deep like k_edge0.
__global__ __launch_bounds__(256) void k_edge1(float* __restrict__ ws) {
  const int blk = blockIdx.x, i = blk >> 2, part = blk & 3;
  const int tid = threadIdx.x;
  const int w = tid >> 6, lane = tid & 63, sq = (lane >> 4) & 3, idx = lane & 15;
  __shared__ float4 GEO[192];
  __shared__ float wb[4][16][25];    // odd stride: conflict-free
  const float4* XP4 = (const float4*)(ws + WS_XP);
  const unsigned* T1 = (const unsigned*)(ws + WS_TBL) + 1025 * ROWC;  // t=1
  const uint2* HSB = (const uint2*)(ws + WS_HSB);
  const uint2* HVB = (const uint2*)(ws + WS_HVB);
  const float4 xi = XP4[i];
  if (tid < 192) {
    int j = part * 192 + tid;
    float4 xj = XP4[j];
    float dx = xi.x - xj.x, dy = xi.y - xj.y, dz = xi.z - xj.z;
    float r2 = dx * dx + dy * dy + dz * dz;
    float u, hx, hy, hz;
    if (j == i || r2 <= 0.0f) { u = 1024.0f; hx = hy = hz = 0.0f; }
    else {
      float rinv = rsqrtf(r2);
      hx = dx * rinv; hy = dy * rinv; hz = dz * rinv;
      u = fminf(r2 * rinv * SCALE, 1024.0f);
    }
    GEO[tid] = make_float4(hx, hy, hz, u);
  }
  __syncthreads();
  float s1[4] = {0, 0, 0, 0};
  float v1[4][3] = {};
  float s2 = 0, v2x = 0, v2y = 0, v2z = 0, v3x = 0, v3y = 0, v3z = 0;
  const int jbase = part * 192;
  const int base = w * 48 + sq;
  // ---- pipeline prologue: load iter 0
  float4 g = GEO[base];
  int i0 = (int)g.w;
  float fr = g.w - (float)i0;
  const unsigned* row = T1 + i0 * ROWC;
  uint4 t1 = ((const uint4*)row)[idx];
  uint4 t3 = ((const uint4*)row)[16 + idx];
  unsigned u2 = row[128 + idx];
  unsigned u4 = row[144 + idx];
  unsigned u5 = row[160 + idx];
  uint2 esb = HSB[(jbase + base) * 16 + idx];
  uint2 evb = HVB[(jbase + base) * 16 + idx];
  for (int q = 0; q < 12; ++q) {
    // current stage registers
    float4 gc = g; float frc = fr;
    uint4 t1c = t1, t3c = t3;
    unsigned u2c = u2, u4c = u4, u5c = u5;
    uint2 esc = esb, evc = evb;
    // prefetch next stage
    if (q < 11) {
      int jl = base + (q + 1) * 4;
      g = GEO[jl];
      i0 = (int)g.w;
      fr = g.w - (float)i0;
      const unsigned* rn = T1 + i0 * ROWC;
      t1 = ((const uint4*)rn)[idx];
      t3 = ((const uint4*)rn)[16 + idx];
      u2 = rn[128 + idx];
      u4 = rn[144 + idx];
      u5 = rn[160 + idx];
      esb = HSB[(jbase + jl) * 16 + idx];
      evb = HVB[(jbase + jl) * 16 + idx];
    }
    // compute with current
    float esx = bl(esc.x), esy = bh(esc.x), esz = bl(esc.y), esw = bh(esc.y);
    float evx = bl(evc.x), evy = bh(evc.x), evz = bl(evc.y);
    s1[0] += esx * lp(t1c.x, frc); s1[1] += esy * lp(t1c.y, frc);
    s1[2] += esz * lp(t1c.z, frc); s1[3] += esw * lp(t1c.w, frc);
    float ax = esx * lp(t3c.x, frc), ay = esy * lp(t3c.y, frc);
    float az = esz * lp(t3c.z, frc), aw = esw * lp(t3c.w, frc);
    v1[0][0] += ax * gc.x; v1[0][1] += ax * gc.y; v1[0][2] += ax * gc.z;
    v1[1][0] += ay * gc.x; v1[1][1] += ay * gc.y; v1[1][2] += ay * gc.z;
    v1[2][0] += az * gc.x; v1[2][1] += az * gc.y; v1[2][2] += az * gc.z;
    v1[3][0] += aw * gc.x; v1[3][1] += aw * gc.y; v1[3][2] += aw * gc.z;
    float rr2 = lp(u2c, frc), rr4 = lp(u4c, frc), rr5 = lp(u5c, frc);
    float dt = evx * gc.x + evy * gc.y + evz * gc.z;
    s2 += dt * rr2;
    v2x += evx * rr4; v2y += evy * rr4; v2z += evz * rr4;
    v3x += (evy * gc.z - evz * gc.y) * rr5;
    v3y += (evz * gc.x - evx * gc.z) * rr5;
    v3z += (evx * gc.y - evy * gc.x) * rr5;
  }
  float vals[23] = {s1[0], s1[1], s1[2], s1[3],
                    v1[0][0], v1[0][1], v1[0][2], v1[1][0], v1[1][1], v1[1][2],
                    v1[2][0], v1[2][1], v1[2][2], v1[3][0], v1[3][1], v1[3][2],
                    s2, v2x, v2y, v2z, v3x, v3y, v3z};
#pragma unroll
  for (int k = 0; k < 23; ++k) {
    float v = vals[k];
    v += __shfl_xor(v, 16);
    v += __shfl_xor(v, 32);
    if (lane < 16) wb[w][lane][k] = v;
  }
  __syncthreads();
  for (int s = tid; s < 368; s += 256) {
    int l, sl;
    if (s < 64) { l = s >> 2; sl = s & 3; }
    else if (s < 80) { l = s - 64; sl = 16; }
    else if (s < 272) { int p = s - 80, f = p / 3, c = p - 3 * f; l = f >> 2; sl = 4 + 3 * (f & 3) + c; }
    else if (s < 320) { int p = s - 272, v = p / 3, c = p - 3 * v; l = v; sl = 17 + c; }
    else { int p = s - 320, v = p / 3, c = p - 3 * v; l = v; sl = 20 + c; }
    ws[WS_SLAB1 + (part * Nn + i) * 384 + s] =
        wb[0][l][sl] + wb[1][l][sl] + wb[2][l][sl] + wb[3][l][sl];
  }
}

// ------------------------------------------------------------- post t=1 -----
__global__ __launch_bounds__(256) void k_post1(const float* __restrict__ wmixs,
                                               const float* __restrict__ wmixv,
                                               const float* __restrict__ wgate,
                                               const float* __restrict__ wros,
                                               const float* __restrict__ wrov,
                                               float* __restrict__ ws,
                                               float* __restrict__ out) {
  const int i = blockIdx.x, tid = threadIdx.x;
  __shared__ float agg[368];
  __shared__ float ms[64], mvv[16][3], gate[16], hsn[64], hvns[16][4];
  const float inv = 1.0f / AVGF;
  const float* S = ws + WS_SLAB1 + i * 384;
  for (int s = tid; s < 368; s += 256)
    agg[s] = (S[s] + S[Nn * 384 + s] + S[2 * Nn * 384 + s] + S[3 * Nn * 384 + s]) * inv;
  __syncthreads();
  if (tid < 64) {
    const float* Wm = wmixs + 80 * 64;             // wmixs[1]
    float a = 0;
    for (int p = 0; p < 80; ++p) a = fmaf(agg[p], Wm[p * 64 + tid], a);
    ms[tid] = a;
  } else if (tid < 112) {
    int c = (tid - 64) >> 4, v = (tid - 64) & 15;
    const float* Wv = wmixv + 96 * 16;             // wmixv[1]
    float a = 0;
    for (int p = 0; p < 96; ++p) {
      int ai = (p < 64) ? (80 + p * 3 + c) : (p < 80 ? (272 + (p - 64) * 3 + c)
                                                     : (320 + (p - 80) * 3 + c));
      a = fmaf(agg[ai], Wv[p * 16 + v], a);
    }
    mvv[v][c] = a;
  }
  __syncthreads();
  if (tid < 64) {
    float m = ms[tid];
    hsn[tid] = m / (1.0f + expf(-m));
  } else if (tid < 80) {
    int v = tid - 64;
    const float* Wg = wgate + 64 * 16;             // wgate[1]
    float a = 0;
    for (int f = 0; f < 64; ++f) a = fmaf(ms[f], Wg[f * 16 + v], a);
    gate[v] = 1.0f / (1.0f + expf(-a));
  }
  __syncthreads();
  if (tid < 64) {
    int v = tid >> 2, c = tid & 3;
    hvns[v][c] = (c < 3) ? gate[v] * mvv[v][c] : 0.0f;
  }
  __syncthreads();
  if (tid < 32) {
    const float* Wr = wros + 64 * 32;              // wros[1]
    float a = ws[WS_OS + i * 32 + tid];
    for (int f = 0; f < 64; ++f) a = fmaf(hsn[f], Wr[f * 32 + tid], a);
    out[i * 32 + tid] = a;
  } else if (tid < 80) {
    int p = tid - 32, k = p / 3, c = p - 3 * k;
    const float* Wr = wrov + 16 * 16;              // wrov[1]
    float a = ws[WS_OV + i * 48 + p] + ws[WS_COM + c];
    for (int v = 0; v < 16; ++v) a = fmaf(hvns[v][c], Wr[v * 16 + k], a);
    out[Nn * 32 + i * 48 + p] = a;
  }
}

// ------------------------------------------------------------- launch -------
extern "C" void kernel_launch(void* const* d_in, const int* in_sizes, int n_in,
                              void* d_out, int out_size, void* d_ws, size_t ws_size,
                              hipStream_t stream) {
  const float* x     = (const float*)d_in[0];
  const float* embed = (const float*)d_in[1];
  const float* wns   = (const float*)d_in[2];
  const float* wnv   = (const float*)d_in[3];
  const float* w1    = (const float*)d_in[4];
  const float* b1    = (const float*)d_in[5];
  const float* w2    = (const float*)d_in[6];
  const float* wmixs = (const float*)d_in[7];
  const float* wmixv = (const float*)d_in[8];
  const float* wgate = (const float*)d_in[9];
  const float* wros  = (const float*)d_in[10];
  const float* wrov  = (const float*)d_in[11];
  float* ws = (float*)d_ws;
  float* out = (float*)d_out;

  hipLaunchKernelGGL(k_setup, dim3(259),    dim3(256), 0, stream, x, embed, wns, w1, b1, w2, ws);
  hipLaunchKernelGGL(k_edge0, dim3(Nn * 4), dim3(256), 0, stream, ws);
  hipLaunchKernelGGL(k_post0, dim3(Nn),     dim3(256), 0, stream,
                     wns, wnv, wmixs, wmixv, wgate, wros, wrov, ws);
  hipLaunchKernelGGL(k_edge1, dim3(Nn * 4), dim3(256), 0, stream, ws);
  hipLaunchKernelGGL(k_post1, dim3(Nn),     dim3(256), 0, stream,
                     wmixs, wmixv, wgate, wros, wrov, ws, out);
}